// Round 4
// baseline (9554.823 us; speedup 1.0000x reference)
//
#include <hip/hip_runtime.h>
#include <hip/hip_bf16.h>

#define B_   8
#define T_   12
#define CIN  16
#define HD   96
#define COUT 8
#define CE   112
#define CD   104
#define HW   4096
#define WIMG 64

typedef __hip_bfloat16 bf16;

__device__ __forceinline__ float b2f(bf16 v) { return __bfloat162float(v); }
__device__ __forceinline__ float sigmf_(float x) { return 1.0f / (1.0f + __expf(-x)); }
__device__ __forceinline__ float tanhf_(float x) { return 2.0f / (1.0f + __expf(-2.0f * x)) - 1.0f; }

__device__ __forceinline__ float ldin(const void* p, long i, int f32) {
    return f32 ? ((const float*)p)[i] : b2f(((const bf16*)p)[i]);
}

// ---------------------------------------------------------------------------
// detect: fp32 vs bf16 input dtype by bit-pattern inspection of eWf
// ---------------------------------------------------------------------------
__global__ void detect_k(const void* w, int* flag) {
    if (threadIdx.x == 0 && blockIdx.x == 0) {
        const unsigned short* u = (const unsigned short*)w;
        int bad = 0;
        for (int i = 0; i < 64; i++) {
            unsigned short v = u[i];
            unsigned e = (v >> 7) & 0xFF;
            if (!(v == 0 || (e >= 90 && e <= 128))) bad++;
        }
        *flag = (bad > 8) ? 1 : 0;
    }
}

// ---------------------------------------------------------------------------
// prep: convert all recurrent-loop weights (bf16 or fp32) -> fp32 workspace
// ---------------------------------------------------------------------------
__global__ void prep_k(
    const void* p0, const void* p1, const void* p2, const void* p3,
    const void* p4, const void* p5, const void* p6, const void* p7,
    const void* p8, const void* p9, const void* p10, const void* p11,
    const void* p12, const void* p13, const void* p14, const void* p15,
    float* __restrict__ dst, const int* __restrict__ flag)
{
    const int f32 = *flag;
    const void* srcs[16] = {p0,p1,p2,p3,p4,p5,p6,p7,p8,p9,p10,p11,p12,p13,p14,p15};
    const int sizes[16] = {10752,10752,10752,10752, 96,96,96,96,
                           89856,89856,89856, 96,96,96, 9984, 96};
    int i = blockIdx.x * blockDim.x + threadIdx.x;
    float* d = dst;
    #pragma unroll 1
    for (int s = 0; s < 16; s++) {
        if (i < sizes[s]) { d[i] = ldin(srcs[s], i, f32); return; }
        i -= sizes[s];
        d += sizes[s];
    }
}

// ---------------------------------------------------------------------------
// combine: fold output head conv(oK)+ob then linear(lW)+lb into one conv
// ---------------------------------------------------------------------------
__global__ void combine_k(const void* __restrict__ oK, const void* __restrict__ obv,
                          const void* __restrict__ lW, const void* __restrict__ lb,
                          float* __restrict__ K2, float* __restrict__ b2,
                          const int* __restrict__ flag)
{
    const int f32 = *flag;
    int i = blockIdx.x * blockDim.x + threadIdx.x;
    if (i < HD * 9) {
        float acc[8] = {0,0,0,0,0,0,0,0};
        for (int cd = 0; cd < CD; cd++) {
            float kv = ldin(oK, cd * (HD * 9) + i, f32);
            #pragma unroll
            for (int o = 0; o < 8; o++)
                acc[o] = fmaf(kv, ldin(lW, cd * COUT + o, f32), acc[o]);
        }
        #pragma unroll
        for (int o = 0; o < 8; o++) K2[i * 8 + o] = acc[o];
    }
    if (i < COUT) {
        float a = ldin(lb, i, f32);
        for (int cd = 0; cd < CD; cd++)
            a = fmaf(ldin(obv, cd, f32), ldin(lW, cd * COUT + i, f32), a);
        b2[i] = a;
    }
}

// ---------------------------------------------------------------------------
// repack decoder weights: per (dg 0..23, cd 0..103) a contiguous 112-float
// record: Kf[4][9] | Ki[4][9] | Kc[4][9] | Wo[4]  -> scalar-load friendly
// ---------------------------------------------------------------------------
__global__ void repack_dec_k(const float* __restrict__ Kf, const float* __restrict__ Ki,
                             const float* __restrict__ Kc, const float* __restrict__ dWof,
                             float* __restrict__ Kpack)
{
    int idx = blockIdx.x * 256 + threadIdx.x;
    if (idx >= 24 * 104) return;
    int dg = idx / 104, cd = idx % 104;
    float* o = Kpack + (size_t)idx * 112;
    #pragma unroll 1
    for (int j = 0; j < 4; j++) {
        int d = dg * 4 + j;
        #pragma unroll
        for (int k = 0; k < 9; k++) {
            o[j*9+k]      = Kf[((size_t)d * CD + cd) * 9 + k];
            o[36+j*9+k]   = Ki[((size_t)d * CD + cd) * 9 + k];
            o[72+j*9+k]   = Kc[((size_t)d * CD + cd) * 9 + k];
        }
        o[108+j] = dWof[cd * HD + d];
    }
}

// ---------------------------------------------------------------------------
// encoder step: d-group of 8, 32 FMA per activation load
// grid (16, 12, 8), block 256 over hw
// ---------------------------------------------------------------------------
__global__ __launch_bounds__(256, 2) void enc_step_k(
    const void* __restrict__ x, int t,
    const float* __restrict__ hin, float* __restrict__ hout, float* __restrict__ cst,
    const float* __restrict__ Wf, const float* __restrict__ Wi,
    const float* __restrict__ Wc, const float* __restrict__ Wo,
    const float* __restrict__ bfv, const float* __restrict__ biv,
    const float* __restrict__ bcv, const float* __restrict__ bov,
    int first, const int* __restrict__ flag)
{
    const int f32 = *flag;
    const int hw = blockIdx.x * 256 + threadIdx.x;
    const int d0 = blockIdx.y * 8;
    const int b  = blockIdx.z;

    const long xoff = ((long)(b * T_ + t) * CIN) * HW + hw;
    const float* hp = hin + (size_t)(b * HD) * HW + hw;

    float af[8], ai[8], ag[8], ao[8];
    #pragma unroll
    for (int j = 0; j < 8; j++) { af[j]=0; ai[j]=0; ag[j]=0; ao[j]=0; }

    if (f32) {
        const float* xp = (const float*)x + xoff;
        #pragma unroll 1
        for (int c = 0; c < CIN; c++) {
            float v = xp[c * HW];
            int r = c * HD + d0;
            #pragma unroll
            for (int j = 0; j < 8; j++) {
                af[j] = fmaf(v, Wf[r + j], af[j]);
                ai[j] = fmaf(v, Wi[r + j], ai[j]);
                ag[j] = fmaf(v, Wc[r + j], ag[j]);
                ao[j] = fmaf(v, Wo[r + j], ao[j]);
            }
        }
    } else {
        const bf16* xp = (const bf16*)x + xoff;
        #pragma unroll 1
        for (int c = 0; c < CIN; c++) {
            float v = b2f(xp[c * HW]);
            int r = c * HD + d0;
            #pragma unroll
            for (int j = 0; j < 8; j++) {
                af[j] = fmaf(v, Wf[r + j], af[j]);
                ai[j] = fmaf(v, Wi[r + j], ai[j]);
                ag[j] = fmaf(v, Wc[r + j], ag[j]);
                ao[j] = fmaf(v, Wo[r + j], ao[j]);
            }
        }
    }
    if (!first) {
        #pragma unroll 1
        for (int c = 0; c < HD; c++) {
            float v = hp[(size_t)c * HW];
            int r = (CIN + c) * HD + d0;
            #pragma unroll
            for (int j = 0; j < 8; j++) {
                af[j] = fmaf(v, Wf[r + j], af[j]);
                ai[j] = fmaf(v, Wi[r + j], ai[j]);
                ag[j] = fmaf(v, Wc[r + j], ag[j]);
                ao[j] = fmaf(v, Wo[r + j], ao[j]);
            }
        }
    }
    #pragma unroll
    for (int j = 0; j < 8; j++) {
        int d = d0 + j;
        float fg = sigmf_(af[j] + bfv[d]);
        float ig = sigmf_(ai[j] + biv[d]);
        float gg = tanhf_(ag[j] + bcv[d]);
        float og = sigmf_(ao[j] + bov[d]);
        size_t off = (size_t)(b * HD + d) * HW + hw;
        float cp = first ? 0.0f : cst[off];
        float cn = fmaf(cp, fg, ig * gg);
        cst[off]  = cn;
        hout[off] = tanhf_(cn) * og;
    }
}

// ---------------------------------------------------------------------------
// decoder step v2: 4-pixel vertical register blocking.
// grid (4, 24, 8): 16-row band, d-group(4), batch. block 256 = 64x * 4ygrp.
// thread computes 4 vertically-adjacent pixels x 4 d x {f,i,g,o}.
// 18 loads (6 rows x 3 cols) -> 448 FMA per channel.
// ---------------------------------------------------------------------------
__global__ __launch_bounds__(256, 2) void dec_step_k(
    const void* __restrict__ x, int t,
    const float* __restrict__ hin, float* __restrict__ hout, float* __restrict__ cst,
    const float* __restrict__ Kpack,
    const float* __restrict__ bfv, const float* __restrict__ biv,
    const float* __restrict__ bcv, const float* __restrict__ bov,
    const int* __restrict__ flag)
{
    const int f32 = *flag;
    const int tid = threadIdx.x;
    const int tx = tid & 63;
    const int ty = tid >> 6;
    const int y0 = blockIdx.x * 16 + ty * 4;
    const int dg = blockIdx.y;
    const int d0 = dg * 4;
    const int b  = blockIdx.z;

    // 18 precomputed clamped offsets + validity masks (rows y0-1..y0+4, cols tx-1..tx+1)
    int  ofs[18];
    bool msk[18];
    #pragma unroll
    for (int r = 0; r < 6; r++) {
        int yr = y0 - 1 + r;
        bool rv = ((unsigned)yr < 64u);
        int yc = rv ? yr : (yr < 0 ? 0 : 63);
        #pragma unroll
        for (int dx = 0; dx < 3; dx++) {
            int xc = tx + dx - 1;
            bool cv = ((unsigned)xc < 64u);
            int xcc = cv ? xc : tx;
            ofs[r*3+dx] = yc * WIMG + xcc;
            msk[r*3+dx] = rv && cv;
        }
    }

    float accf[16], acci[16], accg[16], acco[16];
    #pragma unroll
    for (int i = 0; i < 16; i++) { accf[i]=0; acci[i]=0; accg[i]=0; acco[i]=0; }

    const float* wp0 = Kpack + (size_t)(dg * CD) * 112;

    // ---- segment 1: x_t channels (cd = 0..7), dtype decided by flag ----
    const size_t xbase = ((size_t)(b * T_ + t) * COUT) * HW;
    #pragma unroll 1
    for (int cd = 0; cd < COUT; cd++) {
        float v[18];
        if (f32) {
            const float* xb2 = (const float*)x + xbase + (size_t)cd * HW;
            #pragma unroll
            for (int k = 0; k < 18; k++) {
                float t0 = xb2[ofs[k]];
                v[k] = msk[k] ? t0 : 0.0f;
            }
        } else {
            const bf16* xb2 = (const bf16*)x + xbase + (size_t)cd * HW;
            #pragma unroll
            for (int k = 0; k < 18; k++) {
                float t0 = b2f(xb2[ofs[k]]);
                v[k] = msk[k] ? t0 : 0.0f;
            }
        }
        const float* wp = wp0 + (size_t)cd * 112;
        #pragma unroll
        for (int p = 0; p < 4; p++) {
            #pragma unroll
            for (int j = 0; j < 4; j++) {
                int a = p * 4 + j;
                #pragma unroll
                for (int k = 0; k < 9; k++) {
                    int vi = (p + k / 3) * 3 + (k % 3);
                    accf[a] = fmaf(v[vi], wp[j*9+k],    accf[a]);
                    acci[a] = fmaf(v[vi], wp[36+j*9+k], acci[a]);
                    accg[a] = fmaf(v[vi], wp[72+j*9+k], accg[a]);
                }
                acco[a] = fmaf(v[(p+1)*3+1], wp[108+j], acco[a]);
            }
        }
    }

    // ---- segment 2: h channels (cd = 8..103), fp32 state ----
    const float* hb = hin + (size_t)(b * HD) * HW;
    #pragma unroll 1
    for (int c = 0; c < HD; c++) {
        const float* hb2 = hb + (size_t)c * HW;
        float v[18];
        #pragma unroll
        for (int k = 0; k < 18; k++) {
            float t0 = hb2[ofs[k]];
            v[k] = msk[k] ? t0 : 0.0f;
        }
        const float* wp = wp0 + (size_t)(c + COUT) * 112;
        #pragma unroll
        for (int p = 0; p < 4; p++) {
            #pragma unroll
            for (int j = 0; j < 4; j++) {
                int a = p * 4 + j;
                #pragma unroll
                for (int k = 0; k < 9; k++) {
                    int vi = (p + k / 3) * 3 + (k % 3);
                    accf[a] = fmaf(v[vi], wp[j*9+k],    accf[a]);
                    acci[a] = fmaf(v[vi], wp[36+j*9+k], acci[a]);
                    accg[a] = fmaf(v[vi], wp[72+j*9+k], accg[a]);
                }
                acco[a] = fmaf(v[(p+1)*3+1], wp[108+j], acco[a]);
            }
        }
    }

    // ---- epilogue: LSTM pointwise + state write ----
    #pragma unroll
    for (int p = 0; p < 4; p++) {
        int pix = (y0 + p) * WIMG + tx;
        #pragma unroll
        for (int j = 0; j < 4; j++) {
            int a = p * 4 + j;
            int d = d0 + j;
            float fg = sigmf_(accf[a] + bfv[d]);
            float ig = sigmf_(acci[a] + biv[d]);
            float gg = tanhf_(accg[a] + bcv[d]);
            float og = sigmf_(acco[a] + bov[d]);
            size_t off = (size_t)(b * HD + d) * HW + pix;
            float cn = fmaf(cst[off], fg, ig * gg);
            cst[off]  = cn;
            hout[off] = tanhf_(cn) * og;
        }
    }
}

// ---------------------------------------------------------------------------
// output head: conv3x3 with pre-combined K2 (96ch -> 8ch), dtype-flag store
// grid (16, 8)
// ---------------------------------------------------------------------------
__global__ __launch_bounds__(256) void out_step_k(
    const float* __restrict__ h, const float* __restrict__ K2, const float* __restrict__ b2,
    void* __restrict__ out, int t, const int* __restrict__ flag)
{
    const int f32 = *flag;
    const int hw = blockIdx.x * 256 + threadIdx.x;
    const int b  = blockIdx.y;
    const int yy = hw >> 6, xx = hw & 63;

    int  nofs[9];
    bool nval[9];
    #pragma unroll
    for (int dy = -1; dy <= 1; dy++) {
        #pragma unroll
        for (int dx = -1; dx <= 1; dx++) {
            int k = (dy + 1) * 3 + (dx + 1);
            int y2 = yy + dy, x2 = xx + dx;
            bool v = ((unsigned)y2 < 64u) && ((unsigned)x2 < 64u);
            int y2c = v ? y2 : yy;
            int x2c = v ? x2 : xx;
            nofs[k] = y2c * WIMG + x2c;
            nval[k] = v;
        }
    }

    const float* hb = h + (size_t)(b * HD) * HW;
    float acc[8] = {0,0,0,0,0,0,0,0};

    #pragma unroll 1
    for (int c = 0; c < HD; c++) {
        float v[9];
        #pragma unroll
        for (int k = 0; k < 9; k++) {
            float t0 = hb[(size_t)c * HW + nofs[k]];
            v[k] = nval[k] ? t0 : 0.0f;
        }
        #pragma unroll
        for (int k = 0; k < 9; k++) {
            const float* kk = K2 + (c * 9 + k) * COUT;
            #pragma unroll
            for (int o = 0; o < 8; o++)
                acc[o] = fmaf(v[k], kk[o], acc[o]);
        }
    }

    long ob = ((long)(b * T_ + t) * COUT) * HW + hw;
    if (f32) {
        float* op = (float*)out;
        #pragma unroll
        for (int o = 0; o < 8; o++)
            op[ob + o * HW] = acc[o] + b2[o];
    } else {
        bf16* op = (bf16*)out;
        #pragma unroll
        for (int o = 0; o < 8; o++)
            op[ob + o * HW] = __float2bfloat16(acc[o] + b2[o]);
    }
}

// ---------------------------------------------------------------------------
extern "C" void kernel_launch(void* const* d_in, const int* in_sizes, int n_in,
                              void* d_out, int out_size, void* d_ws, size_t ws_size,
                              hipStream_t stream)
{
    const void* enc_in = d_in[0];
    const void* dec_in = d_in[1];
    const void* eWf = d_in[2];  const void* ebf = d_in[3];
    const void* eWi = d_in[4];  const void* ebi = d_in[5];
    const void* eWc = d_in[6];  const void* ebc = d_in[7];
    const void* eWo = d_in[8];  const void* ebo = d_in[9];
    const void* dKf = d_in[10]; const void* dbf = d_in[11];
    const void* dKi = d_in[12]; const void* dbi = d_in[13];
    const void* dKc = d_in[14]; const void* dbc = d_in[15];
    const void* dWo = d_in[16]; const void* dbo = d_in[17];
    const void* oK  = d_in[18]; const void* obv = d_in[19];
    const void* lW  = d_in[20]; const void* lb  = d_in[21];

    int* flag = (int*)d_ws;
    float* ws = (float*)d_ws + 16;

    const int S = B_ * HD * HW;         // 3,145,728 floats per state buffer
    float* hA = ws;
    float* hB = hA + S;
    float* cS = hB + S;
    float* Wbase = cS + S;
    float* Wf   = Wbase;
    float* Wi   = Wf + 10752;
    float* Wc   = Wi + 10752;
    float* Wo   = Wc + 10752;
    float* bfv  = Wo + 10752;
    float* biv  = bfv + 96;
    float* bcv  = biv + 96;
    float* bov  = bcv + 96;
    float* Kf   = bov + 96;
    float* Ki   = Kf + 89856;
    float* Kc   = Ki + 89856;
    float* dbfv = Kc + 89856;
    float* dbiv = dbfv + 96;
    float* dbcv = dbiv + 96;
    float* dWof = dbcv + 96;
    float* dbov = dWof + 9984;
    float* K2   = dbov + 96;
    float* b2   = K2 + 6912;
    float* Kpack = b2 + 16;             // 24*104*112 = 279,552 floats

    detect_k<<<dim3(1), dim3(64), 0, stream>>>(eWf, flag);
    prep_k<<<dim3(1263), dim3(256), 0, stream>>>(
        eWf, eWi, eWc, eWo, ebf, ebi, ebc, ebo,
        dKf, dKi, dKc, dbf, dbi, dbc, dWo, dbo, Wbase, flag);
    combine_k<<<dim3(4), dim3(256), 0, stream>>>(oK, obv, lW, lb, K2, b2, flag);
    repack_dec_k<<<dim3(10), dim3(256), 0, stream>>>(Kf, Ki, Kc, dWof, Kpack);

    float* hin = hA;
    float* hout = hB;
    for (int t = 0; t < T_; t++) {
        enc_step_k<<<dim3(16, 12, B_), dim3(256), 0, stream>>>(
            enc_in, t, hin, hout, cS,
            Wf, Wi, Wc, Wo, bfv, biv, bcv, bov, (t == 0) ? 1 : 0, flag);
        float* tmp = hin; hin = hout; hout = tmp;
    }
    for (int t = 0; t < T_; t++) {
        dec_step_k<<<dim3(4, 24, B_), dim3(256), 0, stream>>>(
            dec_in, t, hin, hout, cS,
            Kpack, dbfv, dbiv, dbcv, dbov, flag);
        float* tmp = hin; hin = hout; hout = tmp;
        out_step_k<<<dim3(16, B_), dim3(256), 0, stream>>>(hin, K2, b2, d_out, t, flag);
    }
}

// Round 5
// 2575.307 us; speedup vs baseline: 3.7102x; 3.7102x over previous
//
#include <hip/hip_runtime.h>
#include <hip/hip_bf16.h>

#define B_   8
#define T_   12
#define CIN  16
#define HD   96
#define COUT 8
#define CE   112
#define CD   104
#define HW   4096
#define WIMG 64

typedef __hip_bfloat16 bf16;
typedef __attribute__((ext_vector_type(8))) short bf16x8;   // 8 bf16 (4 VGPRs)
typedef __attribute__((ext_vector_type(16))) float f32x16;  // MFMA 32x32 C/D

__device__ __forceinline__ float b2f(bf16 v) { return __bfloat162float(v); }
__device__ __forceinline__ float sigmf_(float x) { return 1.0f / (1.0f + __expf(-x)); }
__device__ __forceinline__ float tanhf_(float x) { return 2.0f / (1.0f + __expf(-2.0f * x)) - 1.0f; }

__device__ __forceinline__ float ldin(const void* p, long i, int f32) {
    return f32 ? ((const float*)p)[i] : b2f(((const bf16*)p)[i]);
}
__device__ __forceinline__ short f2bs(float v) {
    __hip_bfloat16 hv = __float2bfloat16(v);
    return *reinterpret_cast<short*>(&hv);
}

// ---------------------------------------------------------------------------
// detect: fp32 vs bf16 input dtype by bit-pattern inspection of eWf
// ---------------------------------------------------------------------------
__global__ void detect_k(const void* w, int* flag) {
    if (threadIdx.x == 0 && blockIdx.x == 0) {
        const unsigned short* u = (const unsigned short*)w;
        int bad = 0;
        for (int i = 0; i < 64; i++) {
            unsigned short v = u[i];
            unsigned e = (v >> 7) & 0xFF;
            if (!(v == 0 || (e >= 90 && e <= 128))) bad++;
        }
        *flag = (bad > 8) ? 1 : 0;
    }
}

// ---------------------------------------------------------------------------
// prep: convert all recurrent-loop weights (bf16 or fp32) -> fp32 workspace
// ---------------------------------------------------------------------------
__global__ void prep_k(
    const void* p0, const void* p1, const void* p2, const void* p3,
    const void* p4, const void* p5, const void* p6, const void* p7,
    const void* p8, const void* p9, const void* p10, const void* p11,
    const void* p12, const void* p13, const void* p14, const void* p15,
    float* __restrict__ dst, const int* __restrict__ flag)
{
    const int f32 = *flag;
    const void* srcs[16] = {p0,p1,p2,p3,p4,p5,p6,p7,p8,p9,p10,p11,p12,p13,p14,p15};
    const int sizes[16] = {10752,10752,10752,10752, 96,96,96,96,
                           89856,89856,89856, 96,96,96, 9984, 96};
    int i = blockIdx.x * blockDim.x + threadIdx.x;
    float* d = dst;
    #pragma unroll 1
    for (int s = 0; s < 16; s++) {
        if (i < sizes[s]) { d[i] = ldin(srcs[s], i, f32); return; }
        i -= sizes[s];
        d += sizes[s];
    }
}

// ---------------------------------------------------------------------------
// combine: fold output head conv(oK)+ob then linear(lW)+lb into one conv
// ---------------------------------------------------------------------------
__global__ void combine_k(const void* __restrict__ oK, const void* __restrict__ obv,
                          const void* __restrict__ lW, const void* __restrict__ lb,
                          float* __restrict__ K2, float* __restrict__ b2,
                          const int* __restrict__ flag)
{
    const int f32 = *flag;
    int i = blockIdx.x * blockDim.x + threadIdx.x;
    if (i < HD * 9) {
        float acc[8] = {0,0,0,0,0,0,0,0};
        for (int cd = 0; cd < CD; cd++) {
            float kv = ldin(oK, cd * (HD * 9) + i, f32);
            #pragma unroll
            for (int o = 0; o < 8; o++)
                acc[o] = fmaf(kv, ldin(lW, cd * COUT + o, f32), acc[o]);
        }
        #pragma unroll
        for (int o = 0; o < 8; o++) K2[i * 8 + o] = acc[o];
    }
    if (i < COUT) {
        float a = ldin(lb, i, f32);
        for (int cd = 0; cd < CD; cd++)
            a = fmaf(ldin(obv, cd, f32), ldin(lW, cd * COUT + i, f32), a);
        b2[i] = a;
    }
}

// ---------------------------------------------------------------------------
// repack decoder weights into MFMA A-fragment order, bf16.
// WtA element layout: [((tap*7 + k0)*12 + mtile)*64 + lane] * 8 + j
// m = mtile*32 + (lane&31); rows 0..95 f, 96..191 i, 192..287 g, 288..383 o
// ch = k0*16 + (lane>>5)*8 + j  (0..111; >=104 zero-padded)
// o-gate rows nonzero only at center tap (tap==4), value dWo[ch][d].
// ---------------------------------------------------------------------------
__global__ void repack_mfma_k(const float* __restrict__ Kf, const float* __restrict__ Ki,
                              const float* __restrict__ Kc, const float* __restrict__ dWof,
                              short* __restrict__ WtA)
{
    int lin = blockIdx.x * 256 + threadIdx.x;
    if (lin >= 9 * 7 * 12 * 64) return;
    int lane = lin & 63;
    int rest = lin >> 6;
    int mt  = rest % 12;
    int k07 = rest / 12;
    int k0  = k07 % 7;
    int tap = k07 / 7;
    int m = mt * 32 + (lane & 31);
    int gate = m / 96, d = m % 96;
    int chb = k0 * 16 + (lane >> 5) * 8;
    #pragma unroll
    for (int j = 0; j < 8; j++) {
        int ch = chb + j;
        float v = 0.f;
        if (ch < 104) {
            if (gate == 0)      v = Kf[((size_t)d * CD + ch) * 9 + tap];
            else if (gate == 1) v = Ki[((size_t)d * CD + ch) * 9 + tap];
            else if (gate == 2) v = Kc[((size_t)d * CD + ch) * 9 + tap];
            else                v = (tap == 4) ? dWof[ch * HD + d] : 0.f;
        }
        WtA[(size_t)lin * 8 + j] = f2bs(v);
    }
}

// ---------------------------------------------------------------------------
// encoder step (fp32 VALU): d-group of 8; h stored bf16, c fp32
// grid (16, 12, 8), block 256 over hw
// ---------------------------------------------------------------------------
__global__ __launch_bounds__(256, 2) void enc_step_k(
    const void* __restrict__ x, int t,
    const bf16* __restrict__ hin, bf16* __restrict__ hout, float* __restrict__ cst,
    const float* __restrict__ Wf, const float* __restrict__ Wi,
    const float* __restrict__ Wc, const float* __restrict__ Wo,
    const float* __restrict__ bfv, const float* __restrict__ biv,
    const float* __restrict__ bcv, const float* __restrict__ bov,
    int first, const int* __restrict__ flag)
{
    const int f32 = *flag;
    const int hw = blockIdx.x * 256 + threadIdx.x;
    const int d0 = blockIdx.y * 8;
    const int b  = blockIdx.z;

    const long xoff = ((long)(b * T_ + t) * CIN) * HW + hw;
    const bf16* hp = hin + (size_t)(b * HD) * HW + hw;

    float af[8], ai[8], ag[8], ao[8];
    #pragma unroll
    for (int j = 0; j < 8; j++) { af[j]=0; ai[j]=0; ag[j]=0; ao[j]=0; }

    if (f32) {
        const float* xp = (const float*)x + xoff;
        #pragma unroll 1
        for (int c = 0; c < CIN; c++) {
            float v = xp[c * HW];
            int r = c * HD + d0;
            #pragma unroll
            for (int j = 0; j < 8; j++) {
                af[j] = fmaf(v, Wf[r + j], af[j]);
                ai[j] = fmaf(v, Wi[r + j], ai[j]);
                ag[j] = fmaf(v, Wc[r + j], ag[j]);
                ao[j] = fmaf(v, Wo[r + j], ao[j]);
            }
        }
    } else {
        const bf16* xp = (const bf16*)x + xoff;
        #pragma unroll 1
        for (int c = 0; c < CIN; c++) {
            float v = b2f(xp[c * HW]);
            int r = c * HD + d0;
            #pragma unroll
            for (int j = 0; j < 8; j++) {
                af[j] = fmaf(v, Wf[r + j], af[j]);
                ai[j] = fmaf(v, Wi[r + j], ai[j]);
                ag[j] = fmaf(v, Wc[r + j], ag[j]);
                ao[j] = fmaf(v, Wo[r + j], ao[j]);
            }
        }
    }
    if (!first) {
        #pragma unroll 1
        for (int c = 0; c < HD; c++) {
            float v = b2f(hp[(size_t)c * HW]);
            int r = (CIN + c) * HD + d0;
            #pragma unroll
            for (int j = 0; j < 8; j++) {
                af[j] = fmaf(v, Wf[r + j], af[j]);
                ai[j] = fmaf(v, Wi[r + j], ai[j]);
                ag[j] = fmaf(v, Wc[r + j], ag[j]);
                ao[j] = fmaf(v, Wo[r + j], ao[j]);
            }
        }
    }
    #pragma unroll
    for (int j = 0; j < 8; j++) {
        int d = d0 + j;
        float fg = sigmf_(af[j] + bfv[d]);
        float ig = sigmf_(ai[j] + biv[d]);
        float gg = tanhf_(ag[j] + bcv[d]);
        float og = sigmf_(ao[j] + bov[d]);
        size_t off = (size_t)(b * HD + d) * HW + hw;
        float cp = first ? 0.0f : cst[off];
        float cn = fmaf(cp, fg, ig * gg);
        cst[off]  = cn;
        hout[off] = __float2bfloat16(tanhf_(cn) * og);
    }
}

// ---------------------------------------------------------------------------
// decoder step: bf16 MFMA implicit GEMM, tap-decomposed.
// grid (32, 3, 8): row-pair, d-tile(32), batch. block 256 = 4 waves.
// LDS: xc tile [4 rows][66 x-slots][120 ch-pitch] bf16 (rows y0-1..y0+2,
// x-slots = x-1..x+1 halo, ch 0..7 = x_t, 8..103 = h, rest zero).
// wave w: pixel row y0+(w>>1), x0=(w&1)*32, one 32x32 C per gate.
// ---------------------------------------------------------------------------
__global__ __launch_bounds__(256) void dec_mfma_k(
    const void* __restrict__ x, int t,
    const bf16* __restrict__ hin, bf16* __restrict__ hout, float* __restrict__ cst,
    const short* __restrict__ WtA,
    const float* __restrict__ bfv, const float* __restrict__ biv,
    const float* __restrict__ bcv, const float* __restrict__ bov,
    const int* __restrict__ flag)
{
    __shared__ short lds[4 * 66 * 120];   // 63,360 B
    const int f32 = *flag;
    const int tid = threadIdx.x;
    const int y0  = blockIdx.x * 2;
    const int dt  = blockIdx.y;
    const int b   = blockIdx.z;

    // ---- stage xc tile ----
    const size_t xbase = (size_t)(b * T_ + t) * COUT * HW;
    const unsigned short* hbase = (const unsigned short*)hin + (size_t)b * HD * HW;
    #pragma unroll 1
    for (int p = tid; p < 264; p += 256) {
        int rl = p / 66, xs = p - rl * 66;
        int y = y0 - 1 + rl;
        int xi = xs - 1;
        short* dstp = &lds[(rl * 66 + xs) * 120];
        if ((unsigned)y < 64u && (unsigned)xi < 64u) {
            int pix = y * WIMG + xi;
            if (f32) {
                const float* xp = (const float*)x + xbase + pix;
                #pragma unroll
                for (int c = 0; c < 8; c++) dstp[c] = f2bs(xp[(size_t)c * HW]);
            } else {
                const unsigned short* xp = (const unsigned short*)x + xbase + pix;
                #pragma unroll
                for (int c = 0; c < 8; c++) dstp[c] = (short)xp[(size_t)c * HW];
            }
            const unsigned short* hp = hbase + pix;
            #pragma unroll 1
            for (int c = 0; c < 96; c++) dstp[8 + c] = (short)hp[(size_t)c * HW];
            #pragma unroll
            for (int c = 104; c < 120; c++) dstp[c] = 0;
        } else {
            #pragma unroll
            for (int c = 0; c < 120; c++) dstp[c] = 0;
        }
    }
    __syncthreads();

    const int wave = tid >> 6, lane = tid & 63;
    const int row_w = 1 + (wave >> 1);
    const int x0 = (wave & 1) * 32;
    const int n = lane & 31, kj = lane >> 5;

    f32x16 accf, acci, accg, acco;
    #pragma unroll
    for (int i = 0; i < 16; i++) { accf[i]=0.f; acci[i]=0.f; accg[i]=0.f; acco[i]=0.f; }

    // ---- K loop: 9 taps x 7 ksteps ----
    #pragma unroll 1
    for (int tap = 0; tap < 9; tap++) {
        int dy = tap / 3 - 1, dx = tap % 3 - 1;
        const short* bbase = &lds[((row_w + dy) * 66 + (1 + x0 + n + dx)) * 120 + kj * 8];
        const short* abase = WtA + ((size_t)(tap * 7) * 12 * 64 + lane) * 8;
        #pragma unroll
        for (int k0 = 0; k0 < 7; k0++) {
            bf16x8 bf = *(const bf16x8*)(bbase + k0 * 16);
            bf16x8 waf = *(const bf16x8*)(abase + (size_t)((k0 * 12 + dt) * 64) * 8);
            bf16x8 wai = *(const bf16x8*)(abase + (size_t)((k0 * 12 + 3 + dt) * 64) * 8);
            bf16x8 wag = *(const bf16x8*)(abase + (size_t)((k0 * 12 + 6 + dt) * 64) * 8);
            accf = __builtin_amdgcn_mfma_f32_32x32x16_bf16(waf, bf, accf, 0, 0, 0);
            acci = __builtin_amdgcn_mfma_f32_32x32x16_bf16(wai, bf, acci, 0, 0, 0);
            accg = __builtin_amdgcn_mfma_f32_32x32x16_bf16(wag, bf, accg, 0, 0, 0);
            if (tap == 4) {
                bf16x8 wao = *(const bf16x8*)(abase + (size_t)((k0 * 12 + 9 + dt) * 64) * 8);
                acco = __builtin_amdgcn_mfma_f32_32x32x16_bf16(wao, bf, acco, 0, 0, 0);
            }
        }
    }

    // ---- epilogue: LSTM pointwise. C map: col=lane&31, row=(r&3)+8*(r>>2)+4*kj
    const int pxi = (y0 + (wave >> 1)) * WIMG + x0 + n;
    #pragma unroll
    for (int r = 0; r < 16; r++) {
        int d = dt * 32 + (r & 3) + 8 * (r >> 2) + 4 * kj;
        float fg = sigmf_(accf[r] + bfv[d]);
        float ig = sigmf_(acci[r] + biv[d]);
        float gg = tanhf_(accg[r] + bcv[d]);
        float og = sigmf_(acco[r] + bov[d]);
        size_t off = ((size_t)b * HD + d) * HW + pxi;
        float cn = fmaf(cst[off], fg, ig * gg);
        cst[off]  = cn;
        hout[off] = __float2bfloat16(tanhf_(cn) * og);
    }
}

// ---------------------------------------------------------------------------
// output head: conv3x3 with pre-combined K2 (96ch -> 8ch); h bf16 in
// grid (16, 8)
// ---------------------------------------------------------------------------
__global__ __launch_bounds__(256) void out_step_k(
    const bf16* __restrict__ h, const float* __restrict__ K2, const float* __restrict__ b2,
    void* __restrict__ out, int t, const int* __restrict__ flag)
{
    const int f32 = *flag;
    const int hw = blockIdx.x * 256 + threadIdx.x;
    const int b  = blockIdx.y;
    const int yy = hw >> 6, xx = hw & 63;

    int  nofs[9];
    bool nval[9];
    #pragma unroll
    for (int dy = -1; dy <= 1; dy++) {
        #pragma unroll
        for (int dx = -1; dx <= 1; dx++) {
            int k = (dy + 1) * 3 + (dx + 1);
            int y2 = yy + dy, x2 = xx + dx;
            bool v = ((unsigned)y2 < 64u) && ((unsigned)x2 < 64u);
            int y2c = v ? y2 : yy;
            int x2c = v ? x2 : xx;
            nofs[k] = y2c * WIMG + x2c;
            nval[k] = v;
        }
    }

    const bf16* hb = h + (size_t)(b * HD) * HW;
    float acc[8] = {0,0,0,0,0,0,0,0};

    #pragma unroll 1
    for (int c = 0; c < HD; c++) {
        float v[9];
        #pragma unroll
        for (int k = 0; k < 9; k++) {
            float t0 = b2f(hb[(size_t)c * HW + nofs[k]]);
            v[k] = nval[k] ? t0 : 0.0f;
        }
        #pragma unroll
        for (int k = 0; k < 9; k++) {
            const float* kk = K2 + (c * 9 + k) * COUT;
            #pragma unroll
            for (int o = 0; o < 8; o++)
                acc[o] = fmaf(v[k], kk[o], acc[o]);
        }
    }

    long ob = ((long)(b * T_ + t) * COUT) * HW + hw;
    if (f32) {
        float* op = (float*)out;
        #pragma unroll
        for (int o = 0; o < 8; o++)
            op[ob + o * HW] = acc[o] + b2[o];
    } else {
        bf16* op = (bf16*)out;
        #pragma unroll
        for (int o = 0; o < 8; o++)
            op[ob + o * HW] = __float2bfloat16(acc[o] + b2[o]);
    }
}

// ---------------------------------------------------------------------------
extern "C" void kernel_launch(void* const* d_in, const int* in_sizes, int n_in,
                              void* d_out, int out_size, void* d_ws, size_t ws_size,
                              hipStream_t stream)
{
    const void* enc_in = d_in[0];
    const void* dec_in = d_in[1];
    const void* eWf = d_in[2];  const void* ebf = d_in[3];
    const void* eWi = d_in[4];  const void* ebi = d_in[5];
    const void* eWc = d_in[6];  const void* ebc = d_in[7];
    const void* eWo = d_in[8];  const void* ebo = d_in[9];
    const void* dKf = d_in[10]; const void* dbf = d_in[11];
    const void* dKi = d_in[12]; const void* dbi = d_in[13];
    const void* dKc = d_in[14]; const void* dbc = d_in[15];
    const void* dWo = d_in[16]; const void* dbo = d_in[17];
    const void* oK  = d_in[18]; const void* obv = d_in[19];
    const void* lW  = d_in[20]; const void* lb  = d_in[21];

    int* flag = (int*)d_ws;
    float* ws = (float*)d_ws + 16;

    const int S = B_ * HD * HW;          // 3,145,728 state elems
    bf16* hA = (bf16*)ws;                // S bf16  (occupies S/2 floats)
    bf16* hB = (bf16*)(ws + S / 2);      // S bf16
    float* cS = ws + S;                  // S floats
    float* Wbase = cS + S;
    float* Wf   = Wbase;
    float* Wi   = Wf + 10752;
    float* Wc   = Wi + 10752;
    float* Wo   = Wc + 10752;
    float* bfv  = Wo + 10752;
    float* biv  = bfv + 96;
    float* bcv  = biv + 96;
    float* bov  = bcv + 96;
    float* Kf   = bov + 96;
    float* Ki   = Kf + 89856;
    float* Kc   = Ki + 89856;
    float* dbfv = Kc + 89856;
    float* dbiv = dbfv + 96;
    float* dbcv = dbiv + 96;
    float* dWof = dbcv + 96;
    float* dbov = dWof + 9984;
    float* K2   = dbov + 96;
    float* b2   = K2 + 6912;
    short* WtA  = (short*)(b2 + 16);     // 9*7*12*64*8 = 387,072 bf16 words

    detect_k<<<dim3(1), dim3(64), 0, stream>>>(eWf, flag);
    prep_k<<<dim3(1263), dim3(256), 0, stream>>>(
        eWf, eWi, eWc, eWo, ebf, ebi, ebc, ebo,
        dKf, dKi, dKc, dbf, dbi, dbc, dWo, dbo, Wbase, flag);
    combine_k<<<dim3(4), dim3(256), 0, stream>>>(oK, obv, lW, lb, K2, b2, flag);
    repack_mfma_k<<<dim3(189), dim3(256), 0, stream>>>(Kf, Ki, Kc, dWof, WtA);

    bf16* hin = hA;
    bf16* hout = hB;
    for (int t = 0; t < T_; t++) {
        enc_step_k<<<dim3(16, 12, B_), dim3(256), 0, stream>>>(
            enc_in, t, hin, hout, cS,
            Wf, Wi, Wc, Wo, bfv, biv, bcv, bov, (t == 0) ? 1 : 0, flag);
        bf16* tmp = hin; hin = hout; hout = tmp;
    }
    for (int t = 0; t < T_; t++) {
        dec_mfma_k<<<dim3(32, 3, B_), dim3(256), 0, stream>>>(
            dec_in, t, hin, hout, cS,
            WtA, dbfv, dbiv, dbcv, dbov, flag);
        bf16* tmp = hin; hin = hout; hout = tmp;
        out_step_k<<<dim3(16, B_), dim3(256), 0, stream>>>(hin, K2, b2, d_out, t, flag);
    }
}

// Round 6
// 2532.017 us; speedup vs baseline: 3.7736x; 1.0171x over previous
//
#include <hip/hip_runtime.h>
#include <hip/hip_bf16.h>

#define B_   8
#define T_   12
#define CIN  16
#define HD   96
#define COUT 8
#define CE   112
#define CD   104
#define HW   4096
#define WIMG 64

typedef __hip_bfloat16 bf16;
typedef __attribute__((ext_vector_type(8))) short bf16x8;   // 8 bf16 (4 VGPRs)
typedef __attribute__((ext_vector_type(16))) float f32x16;  // MFMA 32x32 C/D

__device__ __forceinline__ float b2f(bf16 v) { return __bfloat162float(v); }
__device__ __forceinline__ float sigmf_(float x) { return 1.0f / (1.0f + __expf(-x)); }
__device__ __forceinline__ float tanhf_(float x) { return 2.0f / (1.0f + __expf(-2.0f * x)) - 1.0f; }

__device__ __forceinline__ float ldin(const void* p, long i, int f32) {
    return f32 ? ((const float*)p)[i] : b2f(((const bf16*)p)[i]);
}
__device__ __forceinline__ short f2bs(float v) {
    __hip_bfloat16 hv = __float2bfloat16(v);
    return *reinterpret_cast<short*>(&hv);
}

// ---------------------------------------------------------------------------
// detect: fp32 vs bf16 input dtype by bit-pattern inspection of eWf
// ---------------------------------------------------------------------------
__global__ void detect_k(const void* w, int* flag) {
    if (threadIdx.x == 0 && blockIdx.x == 0) {
        const unsigned short* u = (const unsigned short*)w;
        int bad = 0;
        for (int i = 0; i < 64; i++) {
            unsigned short v = u[i];
            unsigned e = (v >> 7) & 0xFF;
            if (!(v == 0 || (e >= 90 && e <= 128))) bad++;
        }
        *flag = (bad > 8) ? 1 : 0;
    }
}

// ---------------------------------------------------------------------------
// prep: convert all recurrent-loop weights (bf16 or fp32) -> fp32 workspace
// ---------------------------------------------------------------------------
__global__ void prep_k(
    const void* p0, const void* p1, const void* p2, const void* p3,
    const void* p4, const void* p5, const void* p6, const void* p7,
    const void* p8, const void* p9, const void* p10, const void* p11,
    const void* p12, const void* p13, const void* p14, const void* p15,
    float* __restrict__ dst, const int* __restrict__ flag)
{
    const int f32 = *flag;
    const void* srcs[16] = {p0,p1,p2,p3,p4,p5,p6,p7,p8,p9,p10,p11,p12,p13,p14,p15};
    const int sizes[16] = {10752,10752,10752,10752, 96,96,96,96,
                           89856,89856,89856, 96,96,96, 9984, 96};
    int i = blockIdx.x * blockDim.x + threadIdx.x;
    float* d = dst;
    #pragma unroll 1
    for (int s = 0; s < 16; s++) {
        if (i < sizes[s]) { d[i] = ldin(srcs[s], i, f32); return; }
        i -= sizes[s];
        d += sizes[s];
    }
}

// ---------------------------------------------------------------------------
// combine: fold output head conv(oK)+ob then linear(lW)+lb into one conv
// ---------------------------------------------------------------------------
__global__ void combine_k(const void* __restrict__ oK, const void* __restrict__ obv,
                          const void* __restrict__ lW, const void* __restrict__ lb,
                          float* __restrict__ K2, float* __restrict__ b2,
                          const int* __restrict__ flag)
{
    const int f32 = *flag;
    int i = blockIdx.x * blockDim.x + threadIdx.x;
    if (i < HD * 9) {
        float acc[8] = {0,0,0,0,0,0,0,0};
        for (int cd = 0; cd < CD; cd++) {
            float kv = ldin(oK, cd * (HD * 9) + i, f32);
            #pragma unroll
            for (int o = 0; o < 8; o++)
                acc[o] = fmaf(kv, ldin(lW, cd * COUT + o, f32), acc[o]);
        }
        #pragma unroll
        for (int o = 0; o < 8; o++) K2[i * 8 + o] = acc[o];
    }
    if (i < COUT) {
        float a = ldin(lb, i, f32);
        for (int cd = 0; cd < CD; cd++)
            a = fmaf(ldin(obv, cd, f32), ldin(lW, cd * COUT + i, f32), a);
        b2[i] = a;
    }
}

// ---------------------------------------------------------------------------
// repack decoder weights into MFMA A-fragment order (unchanged from r5):
// WtA[((tap*7 + k0)*12 + mt)*64 + lane]*8+j ; m=mt*32+(lane&31);
// gate=m/96 (f,i,g,o), d=m%96; ch = k0*16+(lane>>5)*8+j (0..111, >=104 pad)
// ---------------------------------------------------------------------------
__global__ void repack_mfma_k(const float* __restrict__ Kf, const float* __restrict__ Ki,
                              const float* __restrict__ Kc, const float* __restrict__ dWof,
                              short* __restrict__ WtA)
{
    int lin = blockIdx.x * 256 + threadIdx.x;
    if (lin >= 9 * 7 * 12 * 64) return;
    int lane = lin & 63;
    int rest = lin >> 6;
    int mt  = rest % 12;
    int k07 = rest / 12;
    int k0  = k07 % 7;
    int tap = k07 / 7;
    int m = mt * 32 + (lane & 31);
    int gate = m / 96, d = m % 96;
    int chb = k0 * 16 + (lane >> 5) * 8;
    #pragma unroll
    for (int j = 0; j < 8; j++) {
        int ch = chb + j;
        float v = 0.f;
        if (ch < 104) {
            if (gate == 0)      v = Kf[((size_t)d * CD + ch) * 9 + tap];
            else if (gate == 1) v = Ki[((size_t)d * CD + ch) * 9 + tap];
            else if (gate == 2) v = Kc[((size_t)d * CD + ch) * 9 + tap];
            else                v = (tap == 4) ? dWof[ch * HD + d] : 0.f;
        }
        WtA[(size_t)lin * 8 + j] = f2bs(v);
    }
}

// ---------------------------------------------------------------------------
// repack encoder weights: EW[((k0*12 + mt)*64 + lane)*8+j]
// ch' = k0*16 + (lane>>5)*8 + j = row of eW (xc = [x16][h96] = rows 0..111)
// ---------------------------------------------------------------------------
__global__ void repack_enc_k(const float* __restrict__ Wf, const float* __restrict__ Wi,
                             const float* __restrict__ Wc, const float* __restrict__ Wo,
                             short* __restrict__ EW)
{
    int lin = blockIdx.x * 256 + threadIdx.x;
    if (lin >= 7 * 12 * 64) return;
    int lane = lin & 63;
    int rest = lin >> 6;
    int mt = rest % 12;
    int k0 = rest / 12;
    int m = mt * 32 + (lane & 31);
    int gate = m / 96, d = m % 96;
    int chb = k0 * 16 + (lane >> 5) * 8;
    const float* W = (gate == 0) ? Wf : (gate == 1) ? Wi : (gate == 2) ? Wc : Wo;
    #pragma unroll
    for (int j = 0; j < 8; j++)
        EW[(size_t)lin * 8 + j] = f2bs(W[(chb + j) * HD + d]);
}

// ---------------------------------------------------------------------------
// encoder step, MFMA. grid (32, 8): 128-px tile, batch. 4 waves x 32 px.
// LDS record/slot: [x 16][h 96][pad 8] = 120 shorts.
// ---------------------------------------------------------------------------
__global__ __launch_bounds__(256, 1) void enc_mfma_k(
    const void* __restrict__ x, int t,
    const bf16* __restrict__ hPin, bf16* __restrict__ hPout, float* __restrict__ cst,
    const short* __restrict__ EW,
    const float* __restrict__ bfv, const float* __restrict__ biv,
    const float* __restrict__ bcv, const float* __restrict__ bov,
    int first, const int* __restrict__ flag)
{
    __shared__ short lds[128 * 120];     // 30,720 B
    const int f32 = *flag;
    const int tid = threadIdx.x;
    const int pix0 = blockIdx.x * 128;
    const int b = blockIdx.y;

    // x fill: 16 ch x 32 quads = 512 tasks
    #pragma unroll
    for (int it = 0; it < 2; it++) {
        int i = tid + it * 256;
        int ch = i & 15, q = i >> 4;
        size_t base = ((size_t)(b * T_ + t) * CIN + ch) * HW + pix0 + q * 4;
        short v0, v1, v2, v3;
        if (f32) {
            float4 f = *(const float4*)((const float*)x + base);
            v0 = f2bs(f.x); v1 = f2bs(f.y); v2 = f2bs(f.z); v3 = f2bs(f.w);
        } else {
            short4 sv = *(const short4*)((const short*)x + base);
            v0 = sv.x; v1 = sv.y; v2 = sv.z; v3 = sv.w;
        }
        int sb = q * 4;
        lds[(sb + 0) * 120 + ch] = v0;
        lds[(sb + 1) * 120 + ch] = v1;
        lds[(sb + 2) * 120 + ch] = v2;
        lds[(sb + 3) * 120 + ch] = v3;
    }
    // h fill (pixel-major records, 12 chunks of 16B each): 1536 chunks
    if (!first) {
        int4 tmp[6];
        int ss[6], jj[6];
        #pragma unroll
        for (int i = 0; i < 6; i++) {
            int c = tid + i * 256;
            int s = c / 12, j = c - s * 12;
            ss[i] = s; jj[i] = j;
            tmp[i] = *(const int4*)((const short*)hPin +
                     ((size_t)b * HW + pix0 + s) * 96 + j * 8);
        }
        #pragma unroll
        for (int i = 0; i < 6; i++)
            *(int4*)(&lds[ss[i] * 120 + 16 + jj[i] * 8]) = tmp[i];
    }
    __syncthreads();

    const int wave = tid >> 6, lane = tid & 63;
    const int n = lane & 31, kj = lane >> 5;
    const short* rec = &lds[(wave * 32 + n) * 120];

    f32x16 acc[12];
    #pragma unroll
    for (int m = 0; m < 12; m++)
        #pragma unroll
        for (int r = 0; r < 16; r++) acc[m][r] = 0.f;

    const int k0max = first ? 1 : 7;
    #pragma unroll 1
    for (int k0 = 0; k0 < k0max; k0++) {
        bf16x8 bf = *(const bf16x8*)(rec + k0 * 16 + kj * 8);
        const short* a0 = EW + ((size_t)(k0 * 12) * 64 + lane) * 8;
        #pragma unroll
        for (int mt = 0; mt < 12; mt++)
            acc[mt] = __builtin_amdgcn_mfma_f32_32x32x16_bf16(
                *(const bf16x8*)(a0 + (size_t)mt * 512), bf, acc[mt], 0, 0, 0);
    }
    __syncthreads();

    // epilogue: LSTM pointwise; h -> LDS (tight records), c fp32 channel-major
    const int px = wave * 32 + n;
    const int pg = pix0 + px;
    #pragma unroll
    for (int dt = 0; dt < 3; dt++) {
        #pragma unroll
        for (int r = 0; r < 16; r++) {
            int row = (r & 3) + 8 * (r >> 2) + 4 * kj;
            int d = dt * 32 + row;
            float fg = sigmf_(acc[dt][r]     + bfv[d]);
            float ig = sigmf_(acc[3 + dt][r] + biv[d]);
            float gg = tanhf_(acc[6 + dt][r] + bcv[d]);
            float og = sigmf_(acc[9 + dt][r] + bov[d]);
            size_t off = ((size_t)b * HD + d) * HW + pg;
            float cp = first ? 0.0f : cst[off];
            float cn = fmaf(cp, fg, ig * gg);
            cst[off] = cn;
            lds[px * 120 + d] = f2bs(tanhf_(cn) * og);
        }
    }
    __syncthreads();
    // cooperative pixel-major store: 128 records x 192B
    {
        int px2 = tid >> 1, half = tid & 1;
        short* gdst = (short*)hPout + ((size_t)b * HW + pix0 + px2) * 96 + half * 48;
        const short* lsrc = &lds[px2 * 120 + half * 48];
        #pragma unroll
        for (int s2 = 0; s2 < 6; s2++)
            *(int4*)(gdst + s2 * 8) = *(const int4*)(lsrc + s2 * 8);
    }
}

// ---------------------------------------------------------------------------
// decoder step, MFMA v2. grid (32, 8): 2-row band, batch. 4 waves.
// LDS: [4 rows][66 slots][120 shorts] = 63,360 B; record [x 8][h 96][pad 16].
// Each wave: 32 px, all 12 m-tiles (f,i,g x3 dtiles + o x3) in registers.
// ---------------------------------------------------------------------------
__global__ __launch_bounds__(256, 1) void dec_mfma2_k(
    const void* __restrict__ x, int t,
    const bf16* __restrict__ hPin, bf16* __restrict__ hPout,
    bf16* __restrict__ hC, float* __restrict__ cst,
    const short* __restrict__ WtA,
    const float* __restrict__ bfv, const float* __restrict__ biv,
    const float* __restrict__ bcv, const float* __restrict__ bov,
    const int* __restrict__ flag)
{
    __shared__ short lds[4 * 66 * 120];  // 63,360 B
    const int f32 = *flag;
    const int tid = threadIdx.x;
    const int y0 = blockIdx.x * 2;
    const int b  = blockIdx.y;

    // zero pass: halo records (slots 0,65 per row) + pad ch104..119 all slots
    const int4 z4 = make_int4(0, 0, 0, 0);
    #pragma unroll 1
    for (int i = tid; i < 648; i += 256) {
        int addr_sh;
        if (i < 120) {
            int r = i / 30, rem = i % 30;
            int s = (rem / 15) * 65;
            addr_sh = (r * 66 + s) * 120 + (rem % 15) * 8;
        } else {
            int z = i - 120;
            addr_sh = (z >> 1) * 120 + 104 + (z & 1) * 8;
        }
        *(int4*)(&lds[addr_sh]) = z4;
    }
    __syncthreads();

    // h staging: rows y0-1..y0+2, 256 records x 12 chunks = 3072
    {
        int4 tmp[12];
        int ss[12], jj[12];
        #pragma unroll
        for (int i = 0; i < 12; i++) {
            int c = tid + i * 256;
            int s = c / 12, j = c - s * 12;
            ss[i] = s; jj[i] = j;
            int y = y0 - 1 + (s >> 6);
            if ((unsigned)y < 64u) {
                tmp[i] = *(const int4*)((const short*)hPin +
                         ((size_t)b * HW + (size_t)(y0 - 1) * 64 + s) * 96 + j * 8);
            } else tmp[i] = z4;
        }
        #pragma unroll
        for (int i = 0; i < 12; i++) {
            int s = ss[i];
            *(int4*)(&lds[((s >> 6) * 66 + 1 + (s & 63)) * 120 + 8 + jj[i] * 8]) = tmp[i];
        }
    }
    // x staging: 4 rows x 8 ch x 16 quads = 512 tasks
    #pragma unroll
    for (int it = 0; it < 2; it++) {
        int i = tid + it * 256;
        int ch = i & 7, q = (i >> 3) & 15, r = i >> 7;
        int y = y0 - 1 + r;
        short v0 = 0, v1 = 0, v2 = 0, v3 = 0;
        if ((unsigned)y < 64u) {
            size_t base = ((size_t)(b * T_ + t) * COUT + ch) * HW + y * 64 + q * 4;
            if (f32) {
                float4 f = *(const float4*)((const float*)x + base);
                v0 = f2bs(f.x); v1 = f2bs(f.y); v2 = f2bs(f.z); v3 = f2bs(f.w);
            } else {
                short4 sv = *(const short4*)((const short*)x + base);
                v0 = sv.x; v1 = sv.y; v2 = sv.z; v3 = sv.w;
            }
        }
        int sb = r * 66 + 1 + q * 4;
        lds[(sb + 0) * 120 + ch] = v0;
        lds[(sb + 1) * 120 + ch] = v1;
        lds[(sb + 2) * 120 + ch] = v2;
        lds[(sb + 3) * 120 + ch] = v3;
    }
    __syncthreads();

    const int wave = tid >> 6, lane = tid & 63;
    const int n = lane & 31, kj = lane >> 5;
    const int rw = 1 + (wave >> 1);
    const int x0 = (wave & 1) * 32;

    f32x16 aF[9], aO[3];
    #pragma unroll
    for (int m = 0; m < 9; m++)
        #pragma unroll
        for (int r = 0; r < 16; r++) aF[m][r] = 0.f;
    #pragma unroll
    for (int m = 0; m < 3; m++)
        #pragma unroll
        for (int r = 0; r < 16; r++) aO[m][r] = 0.f;

    // conv gates f,i,g: 9 taps x 7 ksteps x 9 m-tiles
    #pragma unroll 1
    for (int tap = 0; tap < 9; tap++) {
        int dy = tap / 3 - 1, dx = tap - (tap / 3) * 3 - 1;
        const short* rec = &lds[((rw + dy) * 66 + 1 + x0 + n + dx) * 120];
        const short* ab = WtA + ((size_t)(tap * 7) * 12 * 64 + lane) * 8;
        #pragma unroll 1
        for (int k0 = 0; k0 < 7; k0++) {
            bf16x8 bf = *(const bf16x8*)(rec + k0 * 16 + kj * 8);
            const short* a0 = ab + (size_t)k0 * 12 * 64 * 8;
            #pragma unroll
            for (int mt = 0; mt < 9; mt++)
                aF[mt] = __builtin_amdgcn_mfma_f32_32x32x16_bf16(
                    *(const bf16x8*)(a0 + (size_t)mt * 512), bf, aF[mt], 0, 0, 0);
        }
    }
    // o gate: center tap only, m-tiles 9..11
    {
        const short* rec = &lds[(rw * 66 + 1 + x0 + n) * 120];
        const short* ab = WtA + ((size_t)(4 * 7) * 12 * 64 + lane) * 8;
        #pragma unroll 1
        for (int k0 = 0; k0 < 7; k0++) {
            bf16x8 bf = *(const bf16x8*)(rec + k0 * 16 + kj * 8);
            const short* a0 = ab + (size_t)k0 * 12 * 64 * 8 + 9 * 512;
            #pragma unroll
            for (int mt = 0; mt < 3; mt++)
                aO[mt] = __builtin_amdgcn_mfma_f32_32x32x16_bf16(
                    *(const bf16x8*)(a0 + (size_t)mt * 512), bf, aO[mt], 0, 0, 0);
        }
    }
    __syncthreads();

    // epilogue: LSTM pointwise; c fp32 + hC channel-major direct; hP via LDS
    const int px = (wave >> 1) * 64 + x0 + n;       // block-local 0..127
    const int pg = (y0 + (wave >> 1)) * 64 + x0 + n;
    #pragma unroll
    for (int dt = 0; dt < 3; dt++) {
        #pragma unroll
        for (int r = 0; r < 16; r++) {
            int row = (r & 3) + 8 * (r >> 2) + 4 * kj;
            int d = dt * 32 + row;
            float fg = sigmf_(aF[dt][r]     + bfv[d]);
            float ig = sigmf_(aF[3 + dt][r] + biv[d]);
            float gg = tanhf_(aF[6 + dt][r] + bcv[d]);
            float og = sigmf_(aO[dt][r]     + bov[d]);
            size_t off = ((size_t)b * HD + d) * HW + pg;
            float cn = fmaf(cst[off], fg, ig * gg);
            cst[off] = cn;
            float hv = tanhf_(cn) * og;
            hC[off] = __float2bfloat16(hv);
            lds[px * 120 + d] = f2bs(hv);
        }
    }
    __syncthreads();
    // cooperative pixel-major store: 128 records (rows y0,y0+1 contiguous)
    {
        int px2 = tid >> 1, half = tid & 1;
        short* gdst = (short*)hPout + ((size_t)b * HW + (size_t)y0 * 64 + px2) * 96 + half * 48;
        const short* lsrc = &lds[px2 * 120 + half * 48];
        #pragma unroll
        for (int s2 = 0; s2 < 6; s2++)
            *(int4*)(gdst + s2 * 8) = *(const int4*)(lsrc + s2 * 8);
    }
}

// ---------------------------------------------------------------------------
// output head: conv3x3 with pre-combined K2 (96ch -> 8ch); h bf16 ch-major in
// grid (16, 8)
// ---------------------------------------------------------------------------
__global__ __launch_bounds__(256) void out_step_k(
    const bf16* __restrict__ h, const float* __restrict__ K2, const float* __restrict__ b2,
    void* __restrict__ out, int t, const int* __restrict__ flag)
{
    const int f32 = *flag;
    const int hw = blockIdx.x * 256 + threadIdx.x;
    const int b  = blockIdx.y;
    const int yy = hw >> 6, xx = hw & 63;

    int  nofs[9];
    bool nval[9];
    #pragma unroll
    for (int dy = -1; dy <= 1; dy++) {
        #pragma unroll
        for (int dx = -1; dx <= 1; dx++) {
            int k = (dy + 1) * 3 + (dx + 1);
            int y2 = yy + dy, x2 = xx + dx;
            bool v = ((unsigned)y2 < 64u) && ((unsigned)x2 < 64u);
            int y2c = v ? y2 : yy;
            int x2c = v ? x2 : xx;
            nofs[k] = y2c * WIMG + x2c;
            nval[k] = v;
        }
    }

    const bf16* hb = h + (size_t)(b * HD) * HW;
    float acc[8] = {0,0,0,0,0,0,0,0};

    #pragma unroll 1
    for (int c = 0; c < HD; c++) {
        float v[9];
        #pragma unroll
        for (int k = 0; k < 9; k++) {
            float t0 = b2f(hb[(size_t)c * HW + nofs[k]]);
            v[k] = nval[k] ? t0 : 0.0f;
        }
        #pragma unroll
        for (int k = 0; k < 9; k++) {
            const float* kk = K2 + (c * 9 + k) * COUT;
            #pragma unroll
            for (int o = 0; o < 8; o++)
                acc[o] = fmaf(v[k], kk[o], acc[o]);
        }
    }

    long ob = ((long)(b * T_ + t) * COUT) * HW + hw;
    if (f32) {
        float* op = (float*)out;
        #pragma unroll
        for (int o = 0; o < 8; o++)
            op[ob + o * HW] = acc[o] + b2[o];
    } else {
        bf16* op = (bf16*)out;
        #pragma unroll
        for (int o = 0; o < 8; o++)
            op[ob + o * HW] = __float2bfloat16(acc[o] + b2[o]);
    }
}

// ---------------------------------------------------------------------------
extern "C" void kernel_launch(void* const* d_in, const int* in_sizes, int n_in,
                              void* d_out, int out_size, void* d_ws, size_t ws_size,
                              hipStream_t stream)
{
    const void* enc_in = d_in[0];
    const void* dec_in = d_in[1];
    const void* eWf = d_in[2];  const void* ebf = d_in[3];
    const void* eWi = d_in[4];  const void* ebi = d_in[5];
    const void* eWc = d_in[6];  const void* ebc = d_in[7];
    const void* eWo = d_in[8];  const void* ebo = d_in[9];
    const void* dKf = d_in[10]; const void* dbf = d_in[11];
    const void* dKi = d_in[12]; const void* dbi = d_in[13];
    const void* dKc = d_in[14]; const void* dbc = d_in[15];
    const void* dWo = d_in[16]; const void* dbo = d_in[17];
    const void* oK  = d_in[18]; const void* obv = d_in[19];
    const void* lW  = d_in[20]; const void* lb  = d_in[21];

    int* flag = (int*)d_ws;
    float* ws = (float*)d_ws + 16;

    const int S = B_ * HD * HW;            // 3,145,728 state elems
    bf16* hPA = (bf16*)ws;                 // S shorts (pixel-major)
    bf16* hPB = (bf16*)(ws + S / 2);       // S shorts
    bf16* hC  = (bf16*)(ws + S);           // S shorts (channel-major, dec->out)
    float* cS = ws + S + S / 2;            // S floats
    float* Wbase = cS + S;
    float* Wf   = Wbase;
    float* Wi   = Wf + 10752;
    float* Wc   = Wi + 10752;
    float* Wo   = Wc + 10752;
    float* bfv  = Wo + 10752;
    float* biv  = bfv + 96;
    float* bcv  = biv + 96;
    float* bov  = bcv + 96;
    float* Kf   = bov + 96;
    float* Ki   = Kf + 89856;
    float* Kc   = Ki + 89856;
    float* dbfv = Kc + 89856;
    float* dbiv = dbfv + 96;
    float* dbcv = dbiv + 96;
    float* dWof = dbcv + 96;
    float* dbov = dWof + 9984;
    float* K2   = dbov + 96;
    float* b2   = K2 + 6912;
    short* WtA  = (short*)(b2 + 16);       // 387,072 shorts
    short* EW   = (short*)(b2 + 16 + 193536); // 43,008 shorts

    detect_k<<<dim3(1), dim3(64), 0, stream>>>(eWf, flag);
    prep_k<<<dim3(1263), dim3(256), 0, stream>>>(
        eWf, eWi, eWc, eWo, ebf, ebi, ebc, ebo,
        dKf, dKi, dKc, dbf, dbi, dbc, dWo, dbo, Wbase, flag);
    combine_k<<<dim3(4), dim3(256), 0, stream>>>(oK, obv, lW, lb, K2, b2, flag);
    repack_mfma_k<<<dim3(189), dim3(256), 0, stream>>>(Kf, Ki, Kc, dWof, WtA);
    repack_enc_k<<<dim3(21), dim3(256), 0, stream>>>(Wf, Wi, Wc, Wo, EW);

    bf16* hin = hPA;
    bf16* hout = hPB;
    for (int t = 0; t < T_; t++) {
        enc_mfma_k<<<dim3(32, B_), dim3(256), 0, stream>>>(
            enc_in, t, hin, hout, cS,
            EW, bfv, biv, bcv, bov, (t == 0) ? 1 : 0, flag);
        bf16* tmp = hin; hin = hout; hout = tmp;
    }
    for (int t = 0; t < T_; t++) {
        dec_mfma2_k<<<dim3(32, B_), dim3(256), 0, stream>>>(
            dec_in, t, hin, hout, hC, cS,
            WtA, dbfv, dbiv, dbcv, dbov, flag);
        bf16* tmp = hin; hin = hout; hout = tmp;
        out_step_k<<<dim3(16, B_), dim3(256), 0, stream>>>(hC, K2, b2, d_out, t, flag);
    }
}

// Round 8
// 1869.745 us; speedup vs baseline: 5.1102x; 1.3542x over previous
//
#include <hip/hip_runtime.h>
#include <hip/hip_bf16.h>

#define B_   8
#define T_   12
#define CIN  16
#define HD   96
#define COUT 8
#define CE   112
#define CD   104
#define HW   4096
#define WIMG 64

typedef __hip_bfloat16 bf16;
typedef __attribute__((ext_vector_type(8))) short bf16x8;   // 8 bf16 (4 VGPRs)
typedef __attribute__((ext_vector_type(16))) float f32x16;  // MFMA 32x32 C/D

__device__ __forceinline__ float b2f(bf16 v) { return __bfloat162float(v); }
__device__ __forceinline__ float sigmf_(float x) { return 1.0f / (1.0f + __expf(-x)); }
__device__ __forceinline__ float tanhf_(float x) { return 2.0f / (1.0f + __expf(-2.0f * x)) - 1.0f; }

__device__ __forceinline__ float ldin(const void* p, long i, int f32) {
    return f32 ? ((const float*)p)[i] : b2f(((const bf16*)p)[i]);
}
__device__ __forceinline__ short f2bs(float v) {
    __hip_bfloat16 hv = __float2bfloat16(v);
    return *reinterpret_cast<short*>(&hv);
}

// ---------------------------------------------------------------------------
// manual grid barrier: monotonic arrival counter, device-scope atomics.
// Safe by capacity: grid=256 blocks, 1 block/CU min occupancy -> all resident.
// ---------------------------------------------------------------------------
__device__ __forceinline__ void gridbar(int* bar, int target) {
    __syncthreads();
    if (threadIdx.x == 0) {
        __threadfence();                       // release block's writes
        atomicAdd(bar, 1);                     // device-scope arrival
        while (__hip_atomic_load(bar, __ATOMIC_RELAXED,
                                 __HIP_MEMORY_SCOPE_AGENT) < target)
            __builtin_amdgcn_s_sleep(2);
    }
    __syncthreads();
    __threadfence();                           // acquire (invalidate caches)
}

// ---------------------------------------------------------------------------
// detect: fp32 vs bf16 input dtype; also zero the grid barrier counter
// ---------------------------------------------------------------------------
__global__ void detect_k(const void* w, int* flag, int* bar) {
    if (threadIdx.x == 0 && blockIdx.x == 0) {
        const unsigned short* u = (const unsigned short*)w;
        int bad = 0;
        for (int i = 0; i < 64; i++) {
            unsigned short v = u[i];
            unsigned e = (v >> 7) & 0xFF;
            if (!(v == 0 || (e >= 90 && e <= 128))) bad++;
        }
        *flag = (bad > 8) ? 1 : 0;
        *bar = 0;
    }
}

// ---------------------------------------------------------------------------
// prep: convert all recurrent-loop weights (bf16 or fp32) -> fp32 workspace
// ---------------------------------------------------------------------------
__global__ void prep_k(
    const void* p0, const void* p1, const void* p2, const void* p3,
    const void* p4, const void* p5, const void* p6, const void* p7,
    const void* p8, const void* p9, const void* p10, const void* p11,
    const void* p12, const void* p13, const void* p14, const void* p15,
    float* __restrict__ dst, const int* __restrict__ flag)
{
    const int f32 = *flag;
    const void* srcs[16] = {p0,p1,p2,p3,p4,p5,p6,p7,p8,p9,p10,p11,p12,p13,p14,p15};
    const int sizes[16] = {10752,10752,10752,10752, 96,96,96,96,
                           89856,89856,89856, 96,96,96, 9984, 96};
    int i = blockIdx.x * blockDim.x + threadIdx.x;
    float* d = dst;
    #pragma unroll 1
    for (int s = 0; s < 16; s++) {
        if (i < sizes[s]) { d[i] = ldin(srcs[s], i, f32); return; }
        i -= sizes[s];
        d += sizes[s];
    }
}

// ---------------------------------------------------------------------------
// combine: fold output head conv(oK)+ob then linear(lW)+lb into one conv
// ---------------------------------------------------------------------------
__global__ void combine_k(const void* __restrict__ oK, const void* __restrict__ obv,
                          const void* __restrict__ lW, const void* __restrict__ lb,
                          float* __restrict__ K2, float* __restrict__ b2,
                          const int* __restrict__ flag)
{
    const int f32 = *flag;
    int i = blockIdx.x * blockDim.x + threadIdx.x;
    if (i < HD * 9) {
        float acc[8] = {0,0,0,0,0,0,0,0};
        for (int cd = 0; cd < CD; cd++) {
            float kv = ldin(oK, cd * (HD * 9) + i, f32);
            #pragma unroll
            for (int o = 0; o < 8; o++)
                acc[o] = fmaf(kv, ldin(lW, cd * COUT + o, f32), acc[o]);
        }
        #pragma unroll
        for (int o = 0; o < 8; o++) K2[i * 8 + o] = acc[o];
    }
    if (i < COUT) {
        float a = ldin(lb, i, f32);
        for (int cd = 0; cd < CD; cd++)
            a = fmaf(ldin(obv, cd, f32), ldin(lW, cd * COUT + i, f32), a);
        b2[i] = a;
    }
}

// ---------------------------------------------------------------------------
// repack decoder gate weights into MFMA A-fragment order:
// WtA[((tap*7 + k0)*12 + mt)*64 + lane]*8+j ; m=mt*32+(lane&31);
// gate=m/96 (f,i,g,o), d=m%96; ch = k0*16+(lane>>5)*8+j (0..111, >=104 pad)
// rec layout: ch 0..7 = x, 8..103 = h
// ---------------------------------------------------------------------------
__global__ void repack_mfma_k(const float* __restrict__ Kf, const float* __restrict__ Ki,
                              const float* __restrict__ Kc, const float* __restrict__ dWof,
                              short* __restrict__ WtA)
{
    int lin = blockIdx.x * 256 + threadIdx.x;
    if (lin >= 9 * 7 * 12 * 64) return;
    int lane = lin & 63;
    int rest = lin >> 6;
    int mt  = rest % 12;
    int k07 = rest / 12;
    int k0  = k07 % 7;
    int tap = k07 / 7;
    int m = mt * 32 + (lane & 31);
    int gate = m / 96, d = m % 96;
    int chb = k0 * 16 + (lane >> 5) * 8;
    #pragma unroll
    for (int j = 0; j < 8; j++) {
        int ch = chb + j;
        float v = 0.f;
        if (ch < 104) {
            if (gate == 0)      v = Kf[((size_t)d * CD + ch) * 9 + tap];
            else if (gate == 1) v = Ki[((size_t)d * CD + ch) * 9 + tap];
            else if (gate == 2) v = Kc[((size_t)d * CD + ch) * 9 + tap];
            else                v = (tap == 4) ? dWof[ch * HD + d] : 0.f;
        }
        WtA[(size_t)lin * 8 + j] = f2bs(v);
    }
}

// ---------------------------------------------------------------------------
// repack encoder weights: EW[((k0*12 + mt)*64 + lane)*8+j]
// rec layout: ch 0..15 = x, 16..111 = h (matches eW rows directly)
// ---------------------------------------------------------------------------
__global__ void repack_enc_k(const float* __restrict__ Wf, const float* __restrict__ Wi,
                             const float* __restrict__ Wc, const float* __restrict__ Wo,
                             short* __restrict__ EW)
{
    int lin = blockIdx.x * 256 + threadIdx.x;
    if (lin >= 7 * 12 * 64) return;
    int lane = lin & 63;
    int rest = lin >> 6;
    int mt = rest % 12;
    int k0 = rest / 12;
    int m = mt * 32 + (lane & 31);
    int gate = m / 96, d = m % 96;
    int chb = k0 * 16 + (lane >> 5) * 8;
    const float* W = (gate == 0) ? Wf : (gate == 1) ? Wi : (gate == 2) ? Wc : Wo;
    #pragma unroll
    for (int j = 0; j < 8; j++)
        EW[(size_t)lin * 8 + j] = f2bs(W[(chb + j) * HD + d]);
}

// ---------------------------------------------------------------------------
// repack combined out-head conv K2 into one MFMA m-tile (rows 0..7 = out ch):
// K2A[((tap*7 + k0)*64 + lane)*8+j]; k = k0*16+(lane>>5)*8+j -> h ch c = k-8
// ---------------------------------------------------------------------------
__global__ void repack_k2a_k(const float* __restrict__ K2, short* __restrict__ K2A)
{
    int lin = blockIdx.x * 256 + threadIdx.x;
    if (lin >= 9 * 7 * 64) return;
    int lane = lin & 63;
    int rest = lin >> 6;
    int k0 = rest % 7;
    int tap = rest / 7;
    int m = lane & 31;
    int kb = k0 * 16 + (lane >> 5) * 8;
    #pragma unroll
    for (int j = 0; j < 8; j++) {
        int c = kb + j - 8;
        float v = (m < 8 && c >= 0 && c < 96) ? K2[(c * 9 + tap) * 8 + m] : 0.f;
        K2A[(size_t)lin * 8 + j] = f2bs(v);
    }
}

// ---------------------------------------------------------------------------
// persistent kernel: whole enc+dec recurrence. grid 256 = 32 bands x 8 batch,
// block 256 = 4 waves, 1 block/CU. c in registers (48 f32/thread). enc h in
// LDS (zero grid syncs). dec: own 2 rows persist in LDS; halo rows via
// ping-pong global + manual grid barrier. out head fused as extra m-tile.
// ---------------------------------------------------------------------------
__global__ void __launch_bounds__(256, 1) net_k(
    const void* __restrict__ xe, const void* __restrict__ xd,
    short* __restrict__ hPA, short* __restrict__ hPB,
    void* __restrict__ out,
    const short* __restrict__ EW, const short* __restrict__ WtA,
    const short* __restrict__ K2A,
    const float* __restrict__ ebf, const float* __restrict__ ebi,
    const float* __restrict__ ebc, const float* __restrict__ ebo,
    const float* __restrict__ dbf, const float* __restrict__ dbi,
    const float* __restrict__ dbc, const float* __restrict__ dbo,
    const float* __restrict__ b2, const int* __restrict__ flag,
    int* __restrict__ bar)
{
    __shared__ short lds[4 * 66 * 120];       // 63,360 B
    const int f32 = *flag;
    const int tid  = threadIdx.x;
    const int b    = blockIdx.x & 7;
    const int band = blockIdx.x >> 3;         // 0..31
    const int y0   = band * 2;
    const int pix0 = y0 * 64;
    const int wave = tid >> 6, lane = tid & 63;
    const int n = lane & 31, kj = lane >> 5;
    const int px = wave * 32 + n;             // block-local pixel 0..127
    const int pg = pix0 + px;                 // global pixel
    const int4 z4 = make_int4(0, 0, 0, 0);
    int phase = 0;

    float cre[48];
    #pragma unroll
    for (int i = 0; i < 48; i++) cre[i] = 0.f;

    // ================= encoder phase: h entirely in LDS recs [px][120] =====
    #pragma unroll 1
    for (int t = 0; t < T_; t++) {
        // x staging: 16 ch x 32 quads
        #pragma unroll
        for (int it = 0; it < 2; it++) {
            int i = tid + it * 256;
            int ch = i & 15, q = i >> 4;
            size_t base = ((size_t)(b * T_ + t) * CIN + ch) * HW + pix0 + q * 4;
            short v0, v1, v2, v3;
            if (f32) {
                float4 f = *(const float4*)((const float*)xe + base);
                v0 = f2bs(f.x); v1 = f2bs(f.y); v2 = f2bs(f.z); v3 = f2bs(f.w);
            } else {
                short4 sv = *(const short4*)((const short*)xe + base);
                v0 = sv.x; v1 = sv.y; v2 = sv.z; v3 = sv.w;
            }
            int sb = q * 4;
            lds[(sb + 0) * 120 + ch] = v0;
            lds[(sb + 1) * 120 + ch] = v1;
            lds[(sb + 2) * 120 + ch] = v2;
            lds[(sb + 3) * 120 + ch] = v3;
        }
        __syncthreads();

        f32x16 acc[12];
        #pragma unroll
        for (int m = 0; m < 12; m++)
            #pragma unroll
            for (int r = 0; r < 16; r++) acc[m][r] = 0.f;

        const short* rec = &lds[px * 120];
        const int k0max = (t == 0) ? 1 : 7;
        #pragma unroll 1
        for (int k0 = 0; k0 < k0max; k0++) {
            bf16x8 bf = *(const bf16x8*)(rec + k0 * 16 + kj * 8);
            const short* a0 = EW + ((size_t)(k0 * 12) * 64 + lane) * 8;
            #pragma unroll
            for (int mt = 0; mt < 12; mt++)
                acc[mt] = __builtin_amdgcn_mfma_f32_32x32x16_bf16(
                    *(const bf16x8*)(a0 + (size_t)mt * 512), bf, acc[mt], 0, 0, 0);
        }
        __syncthreads();

        // epilogue: LSTM pointwise, c in regs, h -> own LDS rec (+16 offset)
        #pragma unroll
        for (int dt = 0; dt < 3; dt++) {
            #pragma unroll
            for (int r = 0; r < 16; r++) {
                int row = (r & 3) + 8 * (r >> 2) + 4 * kj;
                int d = dt * 32 + row;
                float fg = sigmf_(acc[dt][r]     + ebf[d]);
                float ig = sigmf_(acc[3 + dt][r] + ebi[d]);
                float gg = tanhf_(acc[6 + dt][r] + ebc[d]);
                float og = sigmf_(acc[9 + dt][r] + ebo[d]);
                int ci = dt * 16 + r;
                float cn = fmaf(cre[ci], fg, ig * gg);
                cre[ci] = cn;
                lds[px * 120 + 16 + d] = f2bs(tanhf_(cn) * og);
            }
        }
        __syncthreads();
        if (t == T_ - 1) {
            // publish final enc h to hPA (pixel-major 96-ch records)
            int px2 = tid >> 1, half = tid & 1;
            short* gdst = hPA + ((size_t)b * HW + pix0 + px2) * 96 + half * 48;
            const short* lsrc = &lds[px2 * 120 + 16 + half * 48];
            #pragma unroll
            for (int s2 = 0; s2 < 6; s2++)
                *(int4*)(gdst + s2 * 8) = *(const int4*)(lsrc + s2 * 8);
        }
    }
    phase++; gridbar(bar, phase * 256);

    // ================= decoder phase =====
    #pragma unroll 1
    for (int tt = 0; tt <= T_; tt++) {
        short* hR  = (tt & 1) ? hPB : hPA;    // h_{tt-1}
        short* hWr = (tt & 1) ? hPA : hPB;    // h_tt

        if (tt == 0) {
            // zero pass: edge slots + ch pads
            #pragma unroll 1
            for (int i = tid; i < 648; i += 256) {
                int addr_sh;
                if (i < 120) {
                    int r = i / 30, rem = i % 30;
                    int s = (rem / 15) * 65;
                    addr_sh = (r * 66 + s) * 120 + (rem % 15) * 8;
                } else {
                    int z = i - 120;
                    addr_sh = (z >> 1) * 120 + 104 + (z & 1) * 8;
                }
                *(int4*)(&lds[addr_sh]) = z4;
            }
            __syncthreads();
            // full h staging: 4 rows x 64 recs x 12 chunks
            int4 tmp[12]; int ss2[12], jj2[12];
            #pragma unroll
            for (int i = 0; i < 12; i++) {
                int c2 = tid + i * 256;
                int s = c2 / 12, j = c2 - s * 12;
                ss2[i] = s; jj2[i] = j;
                int y = y0 - 1 + (s >> 6);
                if ((unsigned)y < 64u)
                    tmp[i] = *(const int4*)(hR + ((size_t)b * HW + (size_t)y * 64 + (s & 63)) * 96 + j * 8);
                else tmp[i] = z4;
            }
            #pragma unroll
            for (int i = 0; i < 12; i++) {
                int s = ss2[i];
                *(int4*)(&lds[((s >> 6) * 66 + 1 + (s & 63)) * 120 + 8 + jj2[i] * 8]) = tmp[i];
            }
        } else {
            // halo staging only: rows y0-1 (slot-row 0) and y0+2 (slot-row 3)
            int4 tmp[6]; int ss2[6], jj2[6];
            #pragma unroll
            for (int i = 0; i < 6; i++) {
                int c2 = tid + i * 256;           // 0..1535
                int s = c2 / 12, j = c2 - s * 12; // s 0..127
                int hi = s >> 6;                  // 0 top, 1 bottom
                int y = hi ? (y0 + 2) : (y0 - 1);
                ss2[i] = hi * 3 * 66 + 1 + (s & 63);
                jj2[i] = j;
                if ((unsigned)y < 64u)
                    tmp[i] = *(const int4*)(hR + ((size_t)b * HW + (size_t)y * 64 + (s & 63)) * 96 + j * 8);
                else tmp[i] = z4;
            }
            #pragma unroll
            for (int i = 0; i < 6; i++)
                *(int4*)(&lds[ss2[i] * 120 + 8 + jj2[i] * 8]) = tmp[i];
        }
        // x staging: 4 rows x 8 ch x 16 quads (skip on final out-only pass)
        if (tt < T_) {
            #pragma unroll
            for (int it = 0; it < 2; it++) {
                int i = tid + it * 256;
                int ch = i & 7, q = (i >> 3) & 15, r = i >> 7;
                int y = y0 - 1 + r;
                short v0 = 0, v1 = 0, v2 = 0, v3 = 0;
                if ((unsigned)y < 64u) {
                    size_t base = ((size_t)(b * T_ + tt) * COUT + ch) * HW + y * 64 + q * 4;
                    if (f32) {
                        float4 f = *(const float4*)((const float*)xd + base);
                        v0 = f2bs(f.x); v1 = f2bs(f.y); v2 = f2bs(f.z); v3 = f2bs(f.w);
                    } else {
                        short4 sv = *(const short4*)((const short*)xd + base);
                        v0 = sv.x; v1 = sv.y; v2 = sv.z; v3 = sv.w;
                    }
                }
                int sb = r * 66 + 1 + q * 4;
                lds[(sb + 0) * 120 + ch] = v0;
                lds[(sb + 1) * 120 + ch] = v1;
                lds[(sb + 2) * 120 + ch] = v2;
                lds[(sb + 3) * 120 + ch] = v3;
            }
        }
        __syncthreads();

        const int rw = 1 + (wave >> 1);
        const int x0 = (wave & 1) * 32;

        f32x16 aF[9], aO[3], aOut;
        #pragma unroll
        for (int m = 0; m < 9; m++)
            #pragma unroll
            for (int r = 0; r < 16; r++) aF[m][r] = 0.f;
        #pragma unroll
        for (int m = 0; m < 3; m++)
            #pragma unroll
            for (int r = 0; r < 16; r++) aO[m][r] = 0.f;
        #pragma unroll
        for (int r = 0; r < 16; r++) aOut[r] = 0.f;

        // main tap loop: gates f,i,g (9 m-tiles) + fused out head (1 m-tile)
        #pragma unroll 1
        for (int tap = 0; tap < 9; tap++) {
            int dy = tap / 3 - 1, dx = tap - (tap / 3) * 3 - 1;
            const short* rec = &lds[((rw + dy) * 66 + 1 + x0 + n + dx) * 120];
            const short* ab = WtA + ((size_t)(tap * 7) * 12 * 64 + lane) * 8;
            const short* kb = K2A + ((size_t)(tap * 7) * 64 + lane) * 8;
            #pragma unroll 1
            for (int k0 = 0; k0 < 7; k0++) {
                bf16x8 bf = *(const bf16x8*)(rec + k0 * 16 + kj * 8);
                if (tt < T_) {
                    const short* a0 = ab + (size_t)k0 * 12 * 64 * 8;
                    #pragma unroll
                    for (int mt = 0; mt < 9; mt++)
                        aF[mt] = __builtin_amdgcn_mfma_f32_32x32x16_bf16(
                            *(const bf16x8*)(a0 + (size_t)mt * 512), bf, aF[mt], 0, 0, 0);
                }
                if (tt > 0)
                    aOut = __builtin_amdgcn_mfma_f32_32x32x16_bf16(
                        *(const bf16x8*)(kb + (size_t)k0 * 512), bf, aOut, 0, 0, 0);
            }
        }
        // o gate: center tap only, m-tiles 9..11
        if (tt < T_) {
            const short* rec = &lds[(rw * 66 + 1 + x0 + n) * 120];
            const short* ab = WtA + ((size_t)(4 * 7) * 12 * 64 + lane) * 8;
            #pragma unroll 1
            for (int k0 = 0; k0 < 7; k0++) {
                bf16x8 bf = *(const bf16x8*)(rec + k0 * 16 + kj * 8);
                const short* a0 = ab + (size_t)k0 * 12 * 64 * 8 + 9 * 512;
                #pragma unroll
                for (int mt = 0; mt < 3; mt++)
                    aO[mt] = __builtin_amdgcn_mfma_f32_32x32x16_bf16(
                        *(const bf16x8*)(a0 + (size_t)mt * 512), bf, aO[mt], 0, 0, 0);
            }
        }
        __syncthreads();

        // fused out store for step tt-1 (C rows 0..7 = out channels)
        if (tt > 0) {
            #pragma unroll
            for (int r = 0; r < 4; r++) {
                int o = r + 4 * kj;
                float v = aOut[r] + b2[o];
                size_t oadr = ((size_t)(b * T_ + (tt - 1)) * COUT + o) * HW + pg;
                if (f32) ((float*)out)[oadr] = v;
                else     ((bf16*)out)[oadr] = __float2bfloat16(v);
            }
        }

        if (tt < T_) {
            // epilogue: LSTM pointwise, c in regs, h -> own staged recs
            #pragma unroll
            for (int dt = 0; dt < 3; dt++) {
                #pragma unroll
                for (int r = 0; r < 16; r++) {
                    int row = (r & 3) + 8 * (r >> 2) + 4 * kj;
                    int d = dt * 32 + row;
                    float fg = sigmf_(aF[dt][r]     + dbf[d]);
                    float ig = sigmf_(aF[3 + dt][r] + dbi[d]);
                    float gg = tanhf_(aF[6 + dt][r] + dbc[d]);
                    float og = sigmf_(aO[dt][r]     + dbo[d]);
                    int ci = dt * 16 + r;
                    float cn = fmaf(cre[ci], fg, ig * gg);
                    cre[ci] = cn;
                    float hv = tanhf_(cn) * og;
                    lds[((1 + (px >> 6)) * 66 + 1 + (px & 63)) * 120 + 8 + d] = f2bs(hv);
                }
            }
            __syncthreads();
            // publish own 2 rows to hWr (pixel-major records)
            int px2 = tid >> 1, half = tid & 1;
            short* gdst = hWr + ((size_t)b * HW + pix0 + px2) * 96 + half * 48;
            const short* lsrc = &lds[((1 + (px2 >> 6)) * 66 + 1 + (px2 & 63)) * 120 + 8 + half * 48];
            #pragma unroll
            for (int s2 = 0; s2 < 6; s2++)
                *(int4*)(gdst + s2 * 8) = *(const int4*)(lsrc + s2 * 8);
            phase++; gridbar(bar, phase * 256);
        }
        // no barrier after the final out-only pass (tt == T_)
    }
}

// ---------------------------------------------------------------------------
extern "C" void kernel_launch(void* const* d_in, const int* in_sizes, int n_in,
                              void* d_out, int out_size, void* d_ws, size_t ws_size,
                              hipStream_t stream)
{
    const void* enc_in = d_in[0];
    const void* dec_in = d_in[1];
    const void* eWf = d_in[2];  const void* ebf_ = d_in[3];
    const void* eWi = d_in[4];  const void* ebi_ = d_in[5];
    const void* eWc = d_in[6];  const void* ebc_ = d_in[7];
    const void* eWo = d_in[8];  const void* ebo_ = d_in[9];
    const void* dKf = d_in[10]; const void* dbf_ = d_in[11];
    const void* dKi = d_in[12]; const void* dbi_ = d_in[13];
    const void* dKc = d_in[14]; const void* dbc_ = d_in[15];
    const void* dWo = d_in[16]; const void* dbo_ = d_in[17];
    const void* oK  = d_in[18]; const void* obv = d_in[19];
    const void* lW  = d_in[20]; const void* lb  = d_in[21];

    int* flag = (int*)d_ws;
    int* bar  = (int*)d_ws + 8;
    float* ws = (float*)d_ws + 16;

    const int S = B_ * HD * HW;              // 3,145,728 state elems
    short* hPA = (short*)ws;                 // S shorts (pixel-major h)
    short* hPB = (short*)(ws + S / 2);       // S shorts
    float* Wbase = ws + S;
    float* Wf   = Wbase;
    float* Wi   = Wf + 10752;
    float* Wc   = Wi + 10752;
    float* Wo   = Wc + 10752;
    float* bfv  = Wo + 10752;
    float* biv  = bfv + 96;
    float* bcv  = biv + 96;
    float* bov  = bcv + 96;
    float* Kf   = bov + 96;
    float* Ki   = Kf + 89856;
    float* Kc   = Ki + 89856;
    float* dbfv = Kc + 89856;
    float* dbiv = dbfv + 96;
    float* dbcv = dbiv + 96;
    float* dWof = dbcv + 96;
    float* dbov = dWof + 9984;
    float* K2   = dbov + 96;
    float* b2   = K2 + 6912;
    short* WtA  = (short*)(b2 + 16);                  // 387,072 shorts
    short* EW   = (short*)(b2 + 16 + 193536);         // 43,008 shorts
    short* K2A  = (short*)(b2 + 16 + 193536 + 21504); // 32,256 shorts

    detect_k<<<dim3(1), dim3(64), 0, stream>>>(eWf, flag, bar);
    prep_k<<<dim3(1263), dim3(256), 0, stream>>>(
        eWf, eWi, eWc, eWo, ebf_, ebi_, ebc_, ebo_,
        dKf, dKi, dKc, dbf_, dbi_, dbc_, dWo, dbo_, Wbase, flag);
    combine_k<<<dim3(4), dim3(256), 0, stream>>>(oK, obv, lW, lb, K2, b2, flag);
    repack_mfma_k<<<dim3(189), dim3(256), 0, stream>>>(Kf, Ki, Kc, dWof, WtA);
    repack_enc_k<<<dim3(21), dim3(256), 0, stream>>>(Wf, Wi, Wc, Wo, EW);
    repack_k2a_k<<<dim3(16), dim3(256), 0, stream>>>(K2, K2A);

    net_k<<<dim3(256), dim3(256), 0, stream>>>(
        enc_in, dec_in, hPA, hPB, d_out,
        EW, WtA, K2A,
        bfv, biv, bcv, bov,
        dbfv, dbiv, dbcv, dbov,
        b2, flag, bar);
}